// Round 1
// baseline (246.924 us; speedup 1.0000x reference)
//
#include <hip/hip_runtime.h>
#include <hip/hip_bf16.h>

// LinearAttentionTriton: out_t = Q_t @ (K_t^T @ V_t) @ S,  S = V^T K (fp32)
// N = 262144, D = 64, TRUNK = 128, fp32 in/out.
//
// Round-4: kill the 8-way LDS write conflicts in transpose staging
// (SQ_LDS_BANK_CONFLICT was 4.19M in s_partial) and raise s_partial
// occupancy 2 -> 4 blocks/CU. Staging thread now owns 8 rows x 4 cols and
// writes 4 full 16B granules (ds_write_b128) at granule 17c + r/8:
// per-16-lane group = (c + lane)&7 -> all 8 bank-groups, 2 lanes each = free.
// Fragment-read layout (stride 136) unchanged -> MFMA math identical to the
// verified kernel. s_reduce widened 32 -> 256 blocks.
// ws usage stays 16 KB (just S); 16 MB of partials live in the tail of
// d_out, consumed by s_reduce then overwritten by trunk_kernel.

#define TRUNK 128
#define DD 64
#define NPART 1024         // s_partial blocks; each covers 256 rows (2 chunks)

typedef __bf16 bf16x8 __attribute__((ext_vector_type(8)));
typedef float  f32x4  __attribute__((ext_vector_type(4)));
typedef unsigned int   u32;
typedef unsigned short u16;
typedef u32 u32x4 __attribute__((ext_vector_type(4)));
typedef u32 u32x2 __attribute__((ext_vector_type(2)));

union F8 { bf16x8 v; u16 u[8]; u32x4 q; };

__device__ __forceinline__ u16 f2bf(float x) {
    union { float f; u32 u; } a; a.f = x;
    u32 u = a.u;
    return (u16)((u + 0x7FFFu + ((u >> 16) & 1u)) >> 16);
}
__device__ __forceinline__ u32 pack2(float a, float b) {
    return (u32)f2bf(a) | ((u32)f2bf(b) << 16);
}

#define P_S  72    // stride for 64x64 mats (G/HT/ST): 144 B rows
#define KV_T 136   // stride for transposed K^T/V^T (64 cols x 128 rows): 272 B

// Stage a 128x64 fp32 global tile as bf16 TRANSPOSED into LDS[64][KV_T].
// 256 threads: thread t owns cols c0..c0+3 (c0=(t>>4)*4), rows r0..r0+7
// (r0=(t&15)*8). 8 float4 global loads (lanes {s,s+16,s+32,s+48} form one
// contiguous 64B line), then 4 ds_write_b128, conflict-free (see header).
__device__ __forceinline__ void stage_T256(const float* __restrict__ M, long tb,
                                           u16* __restrict__ MT, int t) {
    const int c0 = (t >> 4) * 4;      // col group 0..60
    const int r0 = (t & 15) * 8;      // row group 0..120
    float4 rw[8];
    #pragma unroll
    for (int i = 0; i < 8; ++i)
        rw[i] = *(const float4*)(M + tb + (long)(r0 + i) * 64 + c0);
    #pragma unroll
    for (int j = 0; j < 4; ++j) {
        u32x4 w;
        w[0] = pack2(((const float*)&rw[0])[j], ((const float*)&rw[1])[j]);
        w[1] = pack2(((const float*)&rw[2])[j], ((const float*)&rw[3])[j]);
        w[2] = pack2(((const float*)&rw[4])[j], ((const float*)&rw[5])[j]);
        w[3] = pack2(((const float*)&rw[6])[j], ((const float*)&rw[7])[j]);
        *(u32x4*)&MT[(c0 + j) * KV_T + r0] = w;   // 16B, granule-aligned
    }
}

// ---------------- Kernel A: per-block MFMA partial of S = V^T K --------------
// 1024 blocks x 256 threads (4 blocks/CU); block accumulates V^T K over
// 2 x 128-row chunks in fp32, writes one 64x64 fp32 partial. No atomics.
__global__ __launch_bounds__(256, 4) void s_partial(const float* __restrict__ K,
                                                    const float* __restrict__ V,
                                                    float* __restrict__ P) {
    __shared__ __align__(16) u16 lds[2 * 64 * KV_T];
    u16* KT = lds;                  // [64][136]
    u16* VT = lds + 64 * KV_T;      // [64][136]

    const int t    = threadIdx.x;
    const int lane = t & 63;
    const int wave = t >> 6;
    const int l15  = lane & 15;
    const int quad = lane >> 4;
    const int mt0  = (wave >> 1) << 1;
    const int nt0  = (wave & 1) << 1;

    f32x4 gacc[2][2] = {};
    const long rowbase = (long)blockIdx.x * 256;

    for (int c = 0; c < 2; ++c) {
        const long tb = (rowbase + c * 128) * 64;
        stage_T256(K, tb, KT, t);
        stage_T256(V, tb, VT, t);
        __syncthreads();
        // C1[b][a] += sum_r V[r][b] K[r][a]  (A = V cols, B = K cols)
        #pragma unroll
        for (int kt = 0; kt < 4; ++kt) {
            const int rbase = kt * 32 + quad * 8;
            F8 af[2], bf[2];
            #pragma unroll
            for (int mi = 0; mi < 2; ++mi)
                af[mi].q = *(const u32x4*)&VT[((mt0 + mi) * 16 + l15) * KV_T + rbase];
            #pragma unroll
            for (int ni = 0; ni < 2; ++ni)
                bf[ni].q = *(const u32x4*)&KT[((nt0 + ni) * 16 + l15) * KV_T + rbase];
            #pragma unroll
            for (int mi = 0; mi < 2; ++mi)
                #pragma unroll
                for (int ni = 0; ni < 2; ++ni)
                    gacc[mi][ni] = __builtin_amdgcn_mfma_f32_16x16x32_bf16(
                        af[mi].v, bf[ni].v, gacc[mi][ni], 0, 0, 0);
        }
        __syncthreads();    // reads done before restaging next chunk
    }

    // write fp32 partial, natural S layout: C row=b (quad*4+reg), col=a (l15)
    float* o = P + (long)blockIdx.x * 4096;
    #pragma unroll
    for (int mi = 0; mi < 2; ++mi)
        #pragma unroll
        for (int ni = 0; ni < 2; ++ni) {
            const int b0 = (mt0 + mi) * 16 + quad * 4;
            const int a  = (nt0 + ni) * 16 + l15;
            const float* g = (const float*)&gacc[mi][ni];
            #pragma unroll
            for (int reg = 0; reg < 4; ++reg)
                o[(b0 + reg) * 64 + a] = g[reg];
        }
}

// ---------------- Kernel A2: reduce 1024 partials -> S (fp32) ----------------
// 65536 threads = 1024 float4-groups x 64 ways; 64 atomics/address. S zeroed.
__global__ __launch_bounds__(256) void s_reduce(const float* __restrict__ P,
                                                float* __restrict__ S) {
    const int tid = blockIdx.x * 256 + threadIdx.x;  // [0, 65536)
    const int eg  = tid & 1023;                       // float4 group of S
    const int way = tid >> 10;                        // [0, 64)
    const float4* p = (const float4*)P;
    float4 acc = {0.f, 0.f, 0.f, 0.f};
    #pragma unroll 4
    for (int i = 0; i < 16; ++i) {
        float4 v = p[(long)(way * 16 + i) * 1024 + eg];
        acc.x += v.x; acc.y += v.y; acc.z += v.z; acc.w += v.w;
    }
    atomicAdd(&S[eg * 4 + 0], acc.x);
    atomicAdd(&S[eg * 4 + 1], acc.y);
    atomicAdd(&S[eg * 4 + 2], acc.z);
    atomicAdd(&S[eg * 4 + 3], acc.w);
}

// ---------------- Kernel B: per-trunk  out = Q (K^T V) S --------------------
// One trunk per 256-thread block. K,V staged transposed at stride 136; all
// MFMA fragments via ds_read_b128. G overlays KT, HT overlays VT after use.
// LDS 44032 B -> 3 blocks/CU.
#define KT_OFF 0                  // [64][136] K^T; later G[a][b] ([64][72])
#define VT_OFF (64 * KV_T)        // [64][136] V^T; later HT[c][a]
#define ST_OFF (2 * 64 * KV_T)    // [64][72]  S^T bf16
#define LDS_ELEMS (2 * 64 * KV_T + 64 * P_S)   // 22016 u16 = 44032 B

__global__ __launch_bounds__(256, 3) void trunk_kernel(const float* __restrict__ Q,
                                                       const float* __restrict__ K,
                                                       const float* __restrict__ V,
                                                       const float* __restrict__ S,
                                                       float* __restrict__ out) {
    __shared__ __align__(16) u16 lds[LDS_ELEMS];
    u16* KT  = lds + KT_OFF;
    u16* VT  = lds + VT_OFF;
    u16* STb = lds + ST_OFF;
    u16* Gb  = lds + KT_OFF;
    u16* HTb = lds + VT_OFF;

    const int t    = threadIdx.x;
    const int lane = t & 63;
    const int wave = t >> 6;
    const int l15  = lane & 15;
    const int quad = lane >> 4;
    const long tb  = (long)blockIdx.x * (TRUNK * DD);

    // ---- prefetch Q fragments (used only in stage 3; hides global latency) --
    F8 a3[2][2];   // [kt][mi]
    #pragma unroll
    for (int kt = 0; kt < 2; ++kt)
        #pragma unroll
        for (int mi = 0; mi < 2; ++mi) {
            const int r = (wave * 2 + mi) * 16 + l15;
            const float* qp = Q + tb + r * 64 + kt * 32 + quad * 8;
            float4 q0 = *(const float4*)qp;
            float4 q1 = *(const float4*)(qp + 4);
            a3[kt][mi].q[0] = pack2(q0.x, q0.y);
            a3[kt][mi].q[1] = pack2(q0.z, q0.w);
            a3[kt][mi].q[2] = pack2(q1.x, q1.y);
            a3[kt][mi].q[3] = pack2(q1.z, q1.w);
        }

    // ---- stage K^T, V^T (conflict-free b128 writes) -------------------------
    stage_T256(K, tb, KT, t);
    stage_T256(V, tb, VT, t);

    // ---- stage S^T: thread owns b-rows sb0..sb0+7, cols sc0..sc0+1 ----------
    // 8 float2 loads (64B-line coalesced), 2 ds_write_b128; group =
    // (c + (t&7))&7 within a phase -> ~2-way (old: 16 scalar 2B writes, 8-way).
    {
        const int sb0 = (t & 7) * 8;        // 0..56
        const int sc0 = (t >> 3) * 2;       // 0..62
        float2 sv[8];
        #pragma unroll
        for (int i = 0; i < 8; ++i)
            sv[i] = *(const float2*)(S + (sb0 + i) * 64 + sc0);
        #pragma unroll
        for (int j = 0; j < 2; ++j) {
            u32x4 w;
            w[0] = pack2(((const float*)&sv[0])[j], ((const float*)&sv[1])[j]);
            w[1] = pack2(((const float*)&sv[2])[j], ((const float*)&sv[3])[j]);
            w[2] = pack2(((const float*)&sv[4])[j], ((const float*)&sv[5])[j]);
            w[3] = pack2(((const float*)&sv[6])[j], ((const float*)&sv[7])[j]);
            *(u32x4*)&STb[(sc0 + j) * P_S + sb0] = w;   // 16B aligned
        }
    }
    __syncthreads();

    // ---- stage 1: C1 = V^T K (m = V-col b, n = K-col a, k = row r) ----------
    const int mt0 = (wave >> 1) << 1;       // 2x2 tile quadrant per wave
    const int nt0 = (wave & 1) << 1;
    f32x4 gacc[2][2] = {};
    #pragma unroll
    for (int kt = 0; kt < 4; ++kt) {
        const int rbase = kt * 32 + quad * 8;
        F8 af[2], bf[2];
        #pragma unroll
        for (int mi = 0; mi < 2; ++mi)
            af[mi].q = *(const u32x4*)&VT[((mt0 + mi) * 16 + l15) * KV_T + rbase];
        #pragma unroll
        for (int ni = 0; ni < 2; ++ni)
            bf[ni].q = *(const u32x4*)&KT[((nt0 + ni) * 16 + l15) * KV_T + rbase];
        #pragma unroll
        for (int mi = 0; mi < 2; ++mi)
            #pragma unroll
            for (int ni = 0; ni < 2; ++ni)
                gacc[mi][ni] = __builtin_amdgcn_mfma_f32_16x16x32_bf16(
                    af[mi].v, bf[ni].v, gacc[mi][ni], 0, 0, 0);
    }
    __syncthreads();   // all KT/VT reads done before overlaying G

    // C1[b][a] = G[a][b]; C-frag row=4*quad+reg, col=l15 -> write G natural
    #pragma unroll
    for (int mi = 0; mi < 2; ++mi)
        #pragma unroll
        for (int ni = 0; ni < 2; ++ni) {
            const int ga  = (nt0 + ni) * 16 + l15;
            const int gb0 = (mt0 + mi) * 16 + quad * 4;
            const float* g = (const float*)&gacc[mi][ni];
            u32x2 w; w[0] = pack2(g[0], g[1]); w[1] = pack2(g[2], g[3]);
            *(u32x2*)&Gb[ga * P_S + gb0] = w;
        }
    __syncthreads();

    // ---- stage 2: H = G @ S  (A = G rows, B = ST rows) ----------------------
    f32x4 hacc[2][2] = {};
    #pragma unroll
    for (int kt = 0; kt < 2; ++kt) {
        const int kb = kt * 32 + quad * 8;
        F8 a2[2], b2[2];
        #pragma unroll
        for (int mi = 0; mi < 2; ++mi)
            a2[mi].q = *(const u32x4*)&Gb[((mt0 + mi) * 16 + l15) * P_S + kb];
        #pragma unroll
        for (int ni = 0; ni < 2; ++ni)
            b2[ni].q = *(const u32x4*)&STb[((nt0 + ni) * 16 + l15) * P_S + kb];
        #pragma unroll
        for (int mi = 0; mi < 2; ++mi)
            #pragma unroll
            for (int ni = 0; ni < 2; ++ni)
                hacc[mi][ni] = __builtin_amdgcn_mfma_f32_16x16x32_bf16(
                    a2[mi].v, b2[ni].v, hacc[mi][ni], 0, 0, 0);
    }
    // write HT[c][a] into VT region (stage-1 reads fenced by prior barrier)
    #pragma unroll
    for (int mi = 0; mi < 2; ++mi)
        #pragma unroll
        for (int ni = 0; ni < 2; ++ni) {
            const int hc  = (nt0 + ni) * 16 + l15;
            const int ha0 = (mt0 + mi) * 16 + quad * 4;
            const float* h = (const float*)&hacc[mi][ni];
            u32x2 w; w[0] = pack2(h[0], h[1]); w[1] = pack2(h[2], h[3]);
            *(u32x2*)&HTb[hc * P_S + ha0] = w;
        }
    __syncthreads();

    // ---- stage 3: out = Q @ H  (A = prefetched Q, B = HT rows) --------------
    f32x4 oacc[2][4] = {};
    #pragma unroll
    for (int kt = 0; kt < 2; ++kt) {
        const int ka = kt * 32 + quad * 8;
        #pragma unroll
        for (int ni = 0; ni < 4; ++ni) {
            F8 bb;
            bb.q = *(const u32x4*)&HTb[(ni * 16 + l15) * P_S + ka];
            #pragma unroll
            for (int mi = 0; mi < 2; ++mi)
                oacc[mi][ni] = __builtin_amdgcn_mfma_f32_16x16x32_bf16(
                    a3[kt][mi].v, bb.v, oacc[mi][ni], 0, 0, 0);
        }
    }
    #pragma unroll
    for (int mi = 0; mi < 2; ++mi)
        #pragma unroll
        for (int ni = 0; ni < 4; ++ni) {
            const int row0 = (wave * 2 + mi) * 16 + quad * 4;
            const int col  = ni * 16 + l15;
            const float* o = (const float*)&oacc[mi][ni];
            #pragma unroll
            for (int reg = 0; reg < 4; ++reg)
                out[tb + (long)(row0 + reg) * 64 + col] = o[reg];
        }
}

extern "C" void kernel_launch(void* const* d_in, const int* in_sizes, int n_in,
                              void* d_out, int out_size, void* d_ws, size_t ws_size,
                              hipStream_t stream) {
    const float* Q = (const float*)d_in[0];
    const float* K = (const float*)d_in[1];
    const float* V = (const float*)d_in[2];
    float* out = (float*)d_out;
    float* S   = (float*)d_ws;                     // 4096 fp32 = 16 KB only

    const int n = in_sizes[0] / DD;                // 262144 rows
    // partials in the tail of d_out (16 MB of 64 MB); consumed by s_reduce,
    // then fully overwritten by trunk_kernel (stream-serialized).
    float* P = out + ((long)out_size - (long)NPART * 4096);

    hipMemsetAsync(S, 0, DD * DD * sizeof(float), stream);
    s_partial<<<NPART, 256, 0, stream>>>(K, V, P);
    s_reduce<<<256, 256, 0, stream>>>(P, S);
    trunk_kernel<<<n / TRUNK, 256, 0, stream>>>(Q, K, V, S, out);
}

// Round 2
// 238.935 us; speedup vs baseline: 1.0334x; 1.0334x over previous
//
#include <hip/hip_runtime.h>
#include <hip/hip_bf16.h>

// LinearAttentionTriton: out_t = Q_t @ (K_t^T @ V_t) @ S,  S = V^T K (fp32)
// N = 262144, D = 64, TRUNK = 128, fp32 in/out.
//
// Round-5 restructure: the per-trunk C1 = V_t^T K_t was computed TWICE
// (s_partial chunks + trunk_kernel stage 1) and K,V were read twice (256 MB
// of 416 MB total traffic). Now:
//   g_kernel  : per trunk, C1 once; writes G_t = C1^T bf16 to global and
//               atomicAdds the fp32 frags into S (replaces s_partial+s_reduce).
//   out_kernel: 2 trunks/block, reads Q + G only (K,V never re-read),
//               stages 2-3 of the old trunk_kernel unchanged.
// G storage is race-free inside d_out: G for trunks {2b,2b+1} sits in the
// first 16 KB of block b's OWN 64 KB out region; each out_kernel block
// drains its G into registers (the first __syncthreads emits vmcnt(0))
// before any out store, and no block touches another block's region.
// Numerics are bit-identical to the verified round-4 kernel on every path
// (same MFMAs, same pack2 bf16 rounding points, fp32 S accumulation).

#define TRUNK 128
#define DD 64

typedef __bf16 bf16x8 __attribute__((ext_vector_type(8)));
typedef float  f32x4  __attribute__((ext_vector_type(4)));
typedef unsigned int   u32;
typedef unsigned short u16;
typedef u32 u32x4 __attribute__((ext_vector_type(4)));
typedef u32 u32x2 __attribute__((ext_vector_type(2)));

union F8 { bf16x8 v; u16 u[8]; u32x4 q; };

__device__ __forceinline__ u16 f2bf(float x) {
    union { float f; u32 u; } a; a.f = x;
    u32 u = a.u;
    return (u16)((u + 0x7FFFu + ((u >> 16) & 1u)) >> 16);
}
__device__ __forceinline__ u32 pack2(float a, float b) {
    return (u32)f2bf(a) | ((u32)f2bf(b) << 16);
}

#define P_S  72    // stride for 64x64 mats (ST/HT): 144 B rows
#define KV_T 136   // stride for transposed K^T/V^T (64 cols x 128 rows): 272 B

// Stage a 128x64 fp32 global tile as bf16 TRANSPOSED into LDS[64][KV_T].
// 256 threads: thread t owns cols c0..c0+3, rows r0..r0+7; 8 float4 global
// loads then 4 ds_write_b128, conflict-free (granule group = (c+lane)&7).
__device__ __forceinline__ void stage_T256(const float* __restrict__ M, long tb,
                                           u16* __restrict__ MT, int t) {
    const int c0 = (t >> 4) * 4;      // col group 0..60
    const int r0 = (t & 15) * 8;      // row group 0..120
    float4 rw[8];
    #pragma unroll
    for (int i = 0; i < 8; ++i)
        rw[i] = *(const float4*)(M + tb + (long)(r0 + i) * 64 + c0);
    #pragma unroll
    for (int j = 0; j < 4; ++j) {
        u32x4 w;
        w[0] = pack2(((const float*)&rw[0])[j], ((const float*)&rw[1])[j]);
        w[1] = pack2(((const float*)&rw[2])[j], ((const float*)&rw[3])[j]);
        w[2] = pack2(((const float*)&rw[4])[j], ((const float*)&rw[5])[j]);
        w[3] = pack2(((const float*)&rw[6])[j], ((const float*)&rw[7])[j]);
        *(u32x4*)&MT[(c0 + j) * KV_T + r0] = w;   // 16B, granule-aligned
    }
}

// ---------------- Kernel 1: per-trunk G_t = (K_t^T V_t), S += C1_t ----------
// 2048 blocks x 256 threads. C1[b][a] = sum_r V[r][b] K[r][a] in fp32 accs;
// G_t[a][b] = C1[b][a] written bf16 at out-embedded slot; fp32 frags
// atomicAdd'ed into S (device-scope, 4096 addresses).
__global__ __launch_bounds__(256, 4) void g_kernel(const float* __restrict__ K,
                                                   const float* __restrict__ V,
                                                   u16* __restrict__ G,
                                                   float* __restrict__ S) {
    __shared__ __align__(16) u16 lds[2 * 64 * KV_T];
    u16* KT = lds;                  // [64][136]
    u16* VT = lds + 64 * KV_T;      // [64][136]

    const int t    = threadIdx.x;
    const int lane = t & 63;
    const int wave = t >> 6;
    const int l15  = lane & 15;
    const int quad = lane >> 4;
    const int mt0  = (wave >> 1) << 1;
    const int nt0  = (wave & 1) << 1;

    const int  tt = blockIdx.x;
    const long tb = (long)tt * (TRUNK * DD);

    stage_T256(K, tb, KT, t);
    stage_T256(V, tb, VT, t);
    __syncthreads();

    f32x4 gacc[2][2] = {};
    #pragma unroll
    for (int kt = 0; kt < 4; ++kt) {
        const int rbase = kt * 32 + quad * 8;
        F8 af[2], bf[2];
        #pragma unroll
        for (int mi = 0; mi < 2; ++mi)
            af[mi].q = *(const u32x4*)&VT[((mt0 + mi) * 16 + l15) * KV_T + rbase];
        #pragma unroll
        for (int ni = 0; ni < 2; ++ni)
            bf[ni].q = *(const u32x4*)&KT[((nt0 + ni) * 16 + l15) * KV_T + rbase];
        #pragma unroll
        for (int mi = 0; mi < 2; ++mi)
            #pragma unroll
            for (int ni = 0; ni < 2; ++ni)
                gacc[mi][ni] = __builtin_amdgcn_mfma_f32_16x16x32_bf16(
                    af[mi].v, bf[ni].v, gacc[mi][ni], 0, 0, 0);
    }

    // G_t slot (u16 units): pair g = tt>>1 at byte g*65536, +8192 if odd trunk.
    u16* Gt = G + ((size_t)(tt >> 1) * 32768 + (size_t)(tt & 1) * 4096);
    #pragma unroll
    for (int mi = 0; mi < 2; ++mi)
        #pragma unroll
        for (int ni = 0; ni < 2; ++ni) {
            const int ga  = (nt0 + ni) * 16 + l15;        // G row a
            const int gb0 = (mt0 + mi) * 16 + quad * 4;   // G col b0..b0+3
            const float* g = (const float*)&gacc[mi][ni];
            u32x2 w; w[0] = pack2(g[0], g[1]); w[1] = pack2(g[2], g[3]);
            *(u32x2*)&Gt[ga * 64 + gb0] = w;
        }

    // S[b][a] += C1[b][a]  (natural layout, fp32 atomics)
    #pragma unroll
    for (int mi = 0; mi < 2; ++mi)
        #pragma unroll
        for (int ni = 0; ni < 2; ++ni) {
            const int b0 = (mt0 + mi) * 16 + quad * 4;
            const int a  = (nt0 + ni) * 16 + l15;
            const float* g = (const float*)&gacc[mi][ni];
            #pragma unroll
            for (int reg = 0; reg < 4; ++reg)
                atomicAdd(&S[(b0 + reg) * 64 + a], g[reg]);
        }
}

// ---------------- Kernel 2: out_t = Q_t @ G_t @ S ---------------------------
// 1024 blocks x 256 threads, 2 trunks each. Reads Q + G (bf16) + S (fp32,
// L2-resident). LDS = S^T + HT only (18432 B). One G-drain barrier, then
// 2 barriers per trunk.
#define LDS3 (2 * 64 * P_S)     // ST (4608 u16) + HT (4608 u16)

__global__ __launch_bounds__(256, 3) void out_kernel(const float* __restrict__ Q,
                                                     const float* __restrict__ S,
                                                     const u16* __restrict__ G,
                                                     float* __restrict__ out) {
    __shared__ __align__(16) u16 lds[LDS3];
    u16* STb = lds;                 // [64][72]  S^T bf16
    u16* HTb = lds + 64 * P_S;      // [64][72]  H^T bf16 (per trunk, reused)

    const int t    = threadIdx.x;
    const int lane = t & 63;
    const int wave = t >> 6;
    const int l15  = lane & 15;
    const int quad = lane >> 4;
    const int mt0  = (wave >> 1) << 1;
    const int nt0  = (wave & 1) << 1;

    // ---- issue G loads for both trunks (A-frags of stage 2) ----------------
    // Frag convention (verified): A row m = a (16B contiguous in k = b).
    const u16* Gblk = G + (size_t)blockIdx.x * 32768;   // this block's 16 KB
    F8 gf[2][2][2];   // [trunk][kt][mi]
    #pragma unroll
    for (int tr = 0; tr < 2; ++tr)
        #pragma unroll
        for (int kt = 0; kt < 2; ++kt)
            #pragma unroll
            for (int mi = 0; mi < 2; ++mi)
                gf[tr][kt][mi].q = *(const u32x4*)&Gblk[(size_t)tr * 4096 +
                    ((mt0 + mi) * 16 + l15) * 64 + kt * 32 + quad * 8];

    // ---- stage S^T into LDS (fp32 S -> bf16, transposed) -------------------
    {
        const int sb0 = (t & 7) * 8;        // 0..56
        const int sc0 = (t >> 3) * 2;       // 0..62
        float2 sv[8];
        #pragma unroll
        for (int i = 0; i < 8; ++i)
            sv[i] = *(const float2*)(S + (sb0 + i) * 64 + sc0);
        #pragma unroll
        for (int j = 0; j < 2; ++j) {
            u32x4 w;
            w[0] = pack2(((const float*)&sv[0])[j], ((const float*)&sv[1])[j]);
            w[1] = pack2(((const float*)&sv[2])[j], ((const float*)&sv[3])[j]);
            w[2] = pack2(((const float*)&sv[4])[j], ((const float*)&sv[5])[j]);
            w[3] = pack2(((const float*)&sv[6])[j], ((const float*)&sv[7])[j]);
            *(u32x4*)&STb[(sc0 + j) * P_S + sb0] = w;   // 16B aligned
        }
    }
    // All G loads must be in registers before ANY out store (stage 3 of
    // trunk 0 overwrites this block's G slots). __syncthreads drains vmcnt(0)
    // per wave before s_barrier; the asm is belt-and-suspenders.
    asm volatile("s_waitcnt vmcnt(0)" ::: "memory");
    __syncthreads();

    #pragma unroll
    for (int tr = 0; tr < 2; ++tr) {
        const long tb = ((long)blockIdx.x * 2 + tr) * (TRUNK * DD);

        // ---- prefetch Q fragments (consumed in stage 3) --------------------
        F8 a3[2][2];   // [kt][mi]
        #pragma unroll
        for (int kt = 0; kt < 2; ++kt)
            #pragma unroll
            for (int mi = 0; mi < 2; ++mi) {
                const int r = (wave * 2 + mi) * 16 + l15;
                const float* qp = Q + tb + r * 64 + kt * 32 + quad * 8;
                float4 q0 = *(const float4*)qp;
                float4 q1 = *(const float4*)(qp + 4);
                a3[kt][mi].q[0] = pack2(q0.x, q0.y);
                a3[kt][mi].q[1] = pack2(q0.z, q0.w);
                a3[kt][mi].q[2] = pack2(q1.x, q1.y);
                a3[kt][mi].q[3] = pack2(q1.z, q1.w);
            }

        // ---- stage 2: H = G @ S  (A = G rows from regs, B = ST rows) -------
        f32x4 hacc[2][2] = {};
        #pragma unroll
        for (int kt = 0; kt < 2; ++kt) {
            const int kb = kt * 32 + quad * 8;
            F8 b2[2];
            #pragma unroll
            for (int ni = 0; ni < 2; ++ni)
                b2[ni].q = *(const u32x4*)&STb[((nt0 + ni) * 16 + l15) * P_S + kb];
            #pragma unroll
            for (int mi = 0; mi < 2; ++mi)
                #pragma unroll
                for (int ni = 0; ni < 2; ++ni)
                    hacc[mi][ni] = __builtin_amdgcn_mfma_f32_16x16x32_bf16(
                        gf[tr][kt][mi].v, b2[ni].v, hacc[mi][ni], 0, 0, 0);
        }
        // write HT[c][a]
        #pragma unroll
        for (int mi = 0; mi < 2; ++mi)
            #pragma unroll
            for (int ni = 0; ni < 2; ++ni) {
                const int hc  = (nt0 + ni) * 16 + l15;
                const int ha0 = (mt0 + mi) * 16 + quad * 4;
                const float* h = (const float*)&hacc[mi][ni];
                u32x2 w; w[0] = pack2(h[0], h[1]); w[1] = pack2(h[2], h[3]);
                *(u32x2*)&HTb[hc * P_S + ha0] = w;
            }
        __syncthreads();

        // ---- stage 3: out = Q @ H  (A = prefetched Q, B = HT rows) ---------
        f32x4 oacc[2][4] = {};
        #pragma unroll
        for (int kt = 0; kt < 2; ++kt) {
            const int ka = kt * 32 + quad * 8;
            #pragma unroll
            for (int ni = 0; ni < 4; ++ni) {
                F8 bb;
                bb.q = *(const u32x4*)&HTb[(ni * 16 + l15) * P_S + ka];
                #pragma unroll
                for (int mi = 0; mi < 2; ++mi)
                    oacc[mi][ni] = __builtin_amdgcn_mfma_f32_16x16x32_bf16(
                        a3[kt][mi].v, bb.v, oacc[mi][ni], 0, 0, 0);
            }
        }
        #pragma unroll
        for (int mi = 0; mi < 2; ++mi)
            #pragma unroll
            for (int ni = 0; ni < 4; ++ni) {
                const int row0 = (wave * 2 + mi) * 16 + quad * 4;
                const int col  = ni * 16 + l15;
                const float* o = (const float*)&oacc[mi][ni];
                #pragma unroll
                for (int reg = 0; reg < 4; ++reg)
                    out[tb + (long)(row0 + reg) * 64 + col] = o[reg];
            }
        if (tr == 0) __syncthreads();   // HTb reads done before next HT write
    }
}

extern "C" void kernel_launch(void* const* d_in, const int* in_sizes, int n_in,
                              void* d_out, int out_size, void* d_ws, size_t ws_size,
                              hipStream_t stream) {
    const float* Q = (const float*)d_in[0];
    const float* K = (const float*)d_in[1];
    const float* V = (const float*)d_in[2];
    float* out = (float*)d_out;
    float* S   = (float*)d_ws;                     // 4096 fp32 = 16 KB only

    const int n = in_sizes[0] / DD;                // 262144 rows
    const int T = n / TRUNK;                       // 2048 trunks

    // G (bf16, 8 KB/trunk, 16 MB total) embedded in d_out: trunk pair
    // {2b, 2b+1} occupies the first 16 KB of out_kernel block b's own 64 KB
    // output region -> fully overwritten by that block only (race-free).
    u16* G = (u16*)out;

    hipMemsetAsync(S, 0, DD * DD * sizeof(float), stream);
    g_kernel<<<T, 256, 0, stream>>>(K, V, G, S);
    out_kernel<<<T / 2, 256, 0, stream>>>(Q, S, G, out);
}